// Round 3
// baseline (129.310 us; speedup 1.0000x reference)
//
#include <hip/hip_runtime.h>
#include <hip/hip_cooperative_groups.h>

// DepthLossForImgBEV: weighted BCE over (B,N,D,H,W) depth logits vs one-hot
// bucketized GT depth, reduced to a scalar mean * 3.0.
//
// B=2 N=6 D=112 H=64 W=176.  depth: (B,N*D,H,W) f32 (60.6 MB); depth_gt:
// (B,N,H,W) f32 (0.54 MB, L2-resident). Memory-bound; roofline ~9.7 us.
//
// Single cooperative kernel (R2's separate 1-block finish kernel cost a
// dispatch + drain gap): per-block partials to d_ws, grid sync, block 0
// reduces.  924 blocks @ __launch_bounds__(256,4) -> 4 blocks/CU guaranteed
// resident (1024 >= 924), no tail round.  Each thread owns one (bn, hw-quad,
// 16-deep d-chunk) column: gt quad + bucket idx hoisted, 16 float4 loads in
// flight.

namespace cg = cooperative_groups;

namespace {

constexpr int B_ = 2, N_ = 6, D_ = 112, H_ = 64, W_ = 176;
constexpr int HW_   = H_ * W_;          // 11264
constexpr int NHWQ_ = HW_ / 4;          // 2816 float4 quads per image plane
constexpr int DPC_  = 16, NCH_ = 7;     // 7 d-chunks x 16 slices = 112
constexpr int NBN_  = B_ * N_;          // 12
constexpr long long TOT_ = (long long)NBN_ * D_ * HW_;   // 15,138,816
constexpr int NTHR_ = NBN_ * NCH_ * NHWQ_;               // 236,544
constexpr int NBLK_ = NTHR_ / 256;                       // 924 blocks
constexpr float SCALE_ = (float)(3.0 / (double)TOT_);    // 3.0 / numel

// bce = min(softplus(+-x), 100) * w;  softplus(x) = relu(x) + log1p(exp(-|x|))
__device__ __forceinline__ float term(float x, float w, bool hit) {
    float c = __logf(1.0f + __expf(-fabsf(x)));          // shared log term
    float r = hit ? fmaxf(-x, 0.0f) : fmaxf(x, 0.0f);
    return w * fminf(c + r, 100.0f);
}

__device__ __forceinline__ int bucket(float g) {
    int i = (int)floorf((g - 2.0f) * 2.0f);   // (g - DBOUND0) / DBOUND2
    return i < 0 ? 0 : (i > D_ ? D_ : i);     // clip [0,D]; D never matches d
}

__global__ __launch_bounds__(256, 4) void depth_loss_coop(
        const float* __restrict__ gt, const float* __restrict__ dp,
        float* __restrict__ part, float* __restrict__ out) {
    const int t    = blockIdx.x * 256 + threadIdx.x;
    const int hwq  = t % NHWQ_;           // quad within image plane
    const int rest = t / NHWQ_;
    const int ch   = rest % NCH_;         // which 16-slice d-chunk
    const int bn   = rest / NCH_;         // (b*N + n)
    const int hw   = hwq * 4;
    const int d0   = ch * DPC_;

    // per-column: weight + bucket index, once for 16 d-slices
    const float4 g = *reinterpret_cast<const float4*>(gt + bn * HW_ + hw);
    const float w0 = (g.x != 0.0f) ? 1.0f : 0.0f;
    const float w1 = (g.y != 0.0f) ? 1.0f : 0.0f;
    const float w2 = (g.z != 0.0f) ? 1.0f : 0.0f;
    const float w3 = (g.w != 0.0f) ? 1.0f : 0.0f;
    const int  i0 = bucket(g.x), i1 = bucket(g.y), i2 = bucket(g.z), i3 = bucket(g.w);

    const float* p = dp + ((bn * D_ + d0) * HW_ + hw);
    float s = 0.0f;
    #pragma unroll
    for (int i = 0; i < DPC_; ++i) {
        const int d = d0 + i;
        float4 x = *reinterpret_cast<const float4*>(p + (size_t)i * HW_);
        s += term(x.x, w0, d == i0);
        s += term(x.y, w1, d == i1);
        s += term(x.z, w2, d == i2);
        s += term(x.w, w3, d == i3);
    }

    // block reduce -> one partial per block
    #pragma unroll
    for (int off = 32; off > 0; off >>= 1) s += __shfl_down(s, off, 64);
    __shared__ float ls[4];
    if ((threadIdx.x & 63) == 0) ls[threadIdx.x >> 6] = s;
    __syncthreads();
    if (threadIdx.x == 0)
        part[blockIdx.x] = (ls[0] + ls[1]) + (ls[2] + ls[3]);

    cg::this_grid().sync();

    // block 0: reduce 924 partials, write the scalar
    if (blockIdx.x == 0) {
        float r = part[threadIdx.x] + part[threadIdx.x + 256] + part[threadIdx.x + 512];
        if (threadIdx.x + 768 < NBLK_) r += part[threadIdx.x + 768];
        #pragma unroll
        for (int off = 32; off > 0; off >>= 1) r += __shfl_down(r, off, 64);
        __syncthreads();                      // ls[] reuse
        if ((threadIdx.x & 63) == 0) ls[threadIdx.x >> 6] = r;
        __syncthreads();
        if (threadIdx.x == 0)
            out[0] = ((ls[0] + ls[1]) + (ls[2] + ls[3])) * SCALE_;
    }
}

}  // namespace

extern "C" void kernel_launch(void* const* d_in, const int* in_sizes, int n_in,
                              void* d_out, int out_size, void* d_ws, size_t ws_size,
                              hipStream_t stream) {
    const float* gt = (const float*)d_in[0];   // depth_gt (B,N,H,W)
    const float* dp = (const float*)d_in[1];   // depth (B,N*D,H,W)
    float* part = (float*)d_ws;                // 924 floats of scratch
    float* out  = (float*)d_out;
    void* args[] = {(void*)&gt, (void*)&dp, (void*)&part, (void*)&out};
    hipLaunchCooperativeKernel((const void*)depth_loss_coop,
                               dim3(NBLK_), dim3(256), args, 0, stream);
}

// Round 4
// 20.780 us; speedup vs baseline: 6.2228x; 6.2228x over previous
//
#include <hip/hip_runtime.h>

// DepthLossForImgBEV: weighted BCE over (B,N,D,H,W) depth logits vs one-hot
// bucketized GT depth, reduced to a scalar mean * 3.0.
//
// B=2 N=6 D=112 H=64 W=176.  depth: (B,N*D,H,W) f32 (60.6 MB); depth_gt:
// (B,N,H,W) f32 (0.54 MB, L2/L3-resident). Memory-bound; roofline ~9.7 us
// HBM (less if L3 keeps the input resident across replays, as R3 showed).
//
// R3 lesson: cooperative fusion compiled to VGPR_Count=16 -> zero memory
// parallelism -> 300 GB/s. Back to two kernels; kernel1 explicitly batches
// all 16 d-slice float4 loads into a register array (static indices) before
// computing, so ~16 x 1KB/wave loads are in flight per thread.

namespace {

constexpr int B_ = 2, N_ = 6, D_ = 112, H_ = 64, W_ = 176;
constexpr int HW_   = H_ * W_;          // 11264
constexpr int NHWQ_ = HW_ / 4;          // 2816 float4 quads per image plane
constexpr int DPC_  = 16, NCH_ = 7;     // 7 d-chunks x 16 slices = 112
constexpr int NBN_  = B_ * N_;          // 12
constexpr long long TOT_ = (long long)NBN_ * D_ * HW_;   // 15,138,816
constexpr int NTHR_ = NBN_ * NCH_ * NHWQ_;               // 236,544
constexpr int NBLK_ = NTHR_ / 256;                       // 924 blocks
constexpr float SCALE_ = (float)(3.0 / (double)TOT_);    // 3.0 / numel

// bce = min(softplus(+-x), 100) * w;  softplus(x) = relu(x) + log1p(exp(-|x|))
__device__ __forceinline__ float term(float x, float w, bool hit) {
    float c = __logf(1.0f + __expf(-fabsf(x)));          // shared log term
    float r = hit ? fmaxf(-x, 0.0f) : fmaxf(x, 0.0f);
    return w * fminf(c + r, 100.0f);
}

__device__ __forceinline__ int bucket(float g) {
    int i = (int)floorf((g - 2.0f) * 2.0f);   // (g - DBOUND0) / DBOUND2
    return i < 0 ? 0 : (i > D_ ? D_ : i);     // clip [0,D]; D never matches d
}

__global__ __launch_bounds__(256) void depth_loss_part(
        const float* __restrict__ gt, const float* __restrict__ dp,
        float* __restrict__ part) {
    const int t    = blockIdx.x * 256 + threadIdx.x;
    const int hwq  = t % NHWQ_;           // quad within image plane
    const int rest = t / NHWQ_;
    const int ch   = rest % NCH_;         // which 16-slice d-chunk
    const int bn   = rest / NCH_;         // (b*N + n)
    const int hw   = hwq * 4;
    const int d0   = ch * DPC_;

    // batch-issue all 16 slice loads (static indices -> registers, 64 VGPRs)
    const float* p = dp + ((bn * D_ + d0) * HW_ + hw);
    float4 xv[DPC_];
    #pragma unroll
    for (int i = 0; i < DPC_; ++i)
        xv[i] = *reinterpret_cast<const float4*>(p + (size_t)i * HW_);

    // per-column weight + bucket index, once for 16 d-slices
    const float4 g = *reinterpret_cast<const float4*>(gt + bn * HW_ + hw);
    const float w0 = (g.x != 0.0f) ? 1.0f : 0.0f;
    const float w1 = (g.y != 0.0f) ? 1.0f : 0.0f;
    const float w2 = (g.z != 0.0f) ? 1.0f : 0.0f;
    const float w3 = (g.w != 0.0f) ? 1.0f : 0.0f;
    const int  i0 = bucket(g.x), i1 = bucket(g.y), i2 = bucket(g.z), i3 = bucket(g.w);

    float s = 0.0f;
    #pragma unroll
    for (int i = 0; i < DPC_; ++i) {
        const int d = d0 + i;
        s += term(xv[i].x, w0, d == i0);
        s += term(xv[i].y, w1, d == i1);
        s += term(xv[i].z, w2, d == i2);
        s += term(xv[i].w, w3, d == i3);
    }

    // block reduce -> one partial per block (overwrite, no init needed)
    #pragma unroll
    for (int off = 32; off > 0; off >>= 1) s += __shfl_down(s, off, 64);
    __shared__ float ls[4];
    if ((threadIdx.x & 63) == 0) ls[threadIdx.x >> 6] = s;
    __syncthreads();
    if (threadIdx.x == 0)
        part[blockIdx.x] = (ls[0] + ls[1]) + (ls[2] + ls[3]);
}

__global__ __launch_bounds__(256) void depth_loss_final(
        const float* __restrict__ part, float* __restrict__ out) {
    float s = part[threadIdx.x] + part[threadIdx.x + 256] + part[threadIdx.x + 512];
    if (threadIdx.x + 768 < NBLK_) s += part[threadIdx.x + 768];
    #pragma unroll
    for (int off = 32; off > 0; off >>= 1) s += __shfl_down(s, off, 64);
    __shared__ float ls[4];
    if ((threadIdx.x & 63) == 0) ls[threadIdx.x >> 6] = s;
    __syncthreads();
    if (threadIdx.x == 0)
        out[0] = ((ls[0] + ls[1]) + (ls[2] + ls[3])) * SCALE_;
}

}  // namespace

extern "C" void kernel_launch(void* const* d_in, const int* in_sizes, int n_in,
                              void* d_out, int out_size, void* d_ws, size_t ws_size,
                              hipStream_t stream) {
    const float* gt = (const float*)d_in[0];   // depth_gt (B,N,H,W)
    const float* dp = (const float*)d_in[1];   // depth (B,N*D,H,W)
    float* part = (float*)d_ws;                // 924 floats of scratch
    float* out  = (float*)d_out;
    depth_loss_part<<<NBLK_, 256, 0, stream>>>(gt, dp, part);
    depth_loss_final<<<1, 256, 0, stream>>>(part, out);
}